// Round 6
// baseline (370.752 us; speedup 1.0000x reference)
//
#include <hip/hip_runtime.h>
#include <hip/hip_bf16.h>

#define EMBED 768
#define DIMQ  800
#define INC   1024
#define NPIX  1024

typedef __bf16 bf16_t;
typedef __bf16 bf16x8 __attribute__((ext_vector_type(8)));
typedef __bf16 bf16x2 __attribute__((ext_vector_type(2)));
typedef float  f32x4  __attribute__((ext_vector_type(4)));

// ---------------- K0: cw convert (plain bf16) + q0 ----------------
__global__ __launch_bounds__(256)
void k_prep(const float* __restrict__ w, bf16_t* __restrict__ cw,
            const float* __restrict__ qkv_w, const float* __restrict__ qkv_b,
            const float* __restrict__ cls, const float* __restrict__ gender,
            float* __restrict__ q0b) {
    const int bi = blockIdx.x;
    const int t  = threadIdx.x;
    if (bi < 200) {
        // ---- q0b[b*800+i] = (Wq t0[b] + bq)[i] ----
        const int wv = t >> 6, tl = t & 63;
        const int i = bi * 4 + wv;                    // 0..799
        const float* row = qkv_w + (size_t)i * DIMQ;
        float ps = 0.f;
        for (int j = tl; j < EMBED; j += 64) ps += row[j] * cls[j];
#pragma unroll
        for (int off = 1; off < 64; off <<= 1) ps += __shfl_xor(ps, off, 64);
        if (tl < 32) {
            float g = 0.f;
#pragma unroll
            for (int j = 0; j < 32; ++j) g += row[EMBED + j] * gender[tl * 32 + j];
            q0b[tl * DIMQ + i] = ps + g + qkv_b[i];
        }
    } else {
        // ---- cw plain convert: B is consumed from L2 into registers now ----
        const int i = (bi - 200) * 256 + t;           // flat [n][k]
        cw[i] = (bf16_t)w[i];
    }
}

// ---------------- K1: u[b][j] = ln_g[j] * sum_o Wk[o][j] q0[b][o] ----------------
__global__ __launch_bounds__(256)
void k_u(const float* __restrict__ qkv_w, const float* __restrict__ q0b,
         const float* __restrict__ ln_g, float* __restrict__ u) {
    __shared__ float q0s[DIMQ];
    __shared__ float sh[8][33];
    int t = threadIdx.x;
    int b  = blockIdx.x / 24;
    int j0 = (blockIdx.x % 24) * 32;
    for (int i = t; i < DIMQ; i += 256) q0s[i] = q0b[b * DIMQ + i];
    __syncthreads();
    int j_l = t & 31, os = t >> 5;
    const float* wk = qkv_w + (size_t)DIMQ * DIMQ;
    const float* wp = wk + (size_t)(os * 100) * DIMQ + j0 + j_l;
    float acc = 0.f;
#pragma unroll 4
    for (int i = 0; i < 100; ++i) acc += wp[(size_t)i * DIMQ] * q0s[os * 100 + i];
    sh[os][j_l] = acc;
    __syncthreads();
    if (t < 32) {
        float s = 0.f;
#pragma unroll
        for (int o = 0; o < 8; ++o) s += sh[o][t];
        u[b * EMBED + j0 + t] = s * ln_g[j0 + t];
    }
}

// ---------------- K2: 128x128xK1024 GEMM, fused x-transpose ----------------
// LDS-bandwidth diet: only A goes through LDS (double-buffered, fused f32->bf16
// transpose with oct-XOR swizzle). B is loaded from L2 straight into a ks-granular
// register ping-pong (bgA/bgB). 48 KB LDS traffic per K-step (was 96). One
// lgkmcnt(0)+s_barrier per tile; all VMEM waits are compiler-counted (register
// consumers). 35840 B LDS -> 3 blocks/CU.
__global__ __launch_bounds__(256, 3)
void k_main(const float* __restrict__ x, const bf16_t* __restrict__ cw,
            const float* __restrict__ conv_b, const float* __restrict__ u,
            float* __restrict__ partial) {
    __shared__ __align__(1024) unsigned char smem[32768 + 3072];
    // A0 @0 ; A1 @16384 ; part @32768 (disjoint)

    const int tid = threadIdx.x;
    const int bi = blockIdx.x;
    const int x8 = bi & 7;                  // -> XCD; 6 nt siblings of an mt on same XCD
    const int s  = bi >> 3;
    const int nt = s % 6;
    const int mt = (s / 6) * 8 + x8;        // 0..255
    const int b  = mt >> 3;
    const int gm = mt * 128;                // global pixel row
    const int gmm = gm & 1023;              // pixel row within this batch image
    const int gn = nt * 128;                // global out-channel

    const int wv = tid >> 6;
    const int l  = tid & 63;

    const int col  = l & 15;
    const int quad = l >> 4;
    const int wm   = (wv >> 1) * 64;
    const int wn   = (wv & 1) * 64;

    bf16_t* A0 = (bf16_t*)smem;
    bf16_t* A1 = (bf16_t*)(smem + 16384);

    // A-stage map: thread owns k-oct (tid&7), m-quad (tid>>3)*4
    const int m4 = (tid >> 3) * 4;          // 0..124
    const float* xsrc = x + ((size_t)(b * 1024 + (tid & 7) * 8) * 1024) + gmm + m4;
    // B per-lane base: row gn+wn+col, k-oct quad (plain cw layout)
    const bf16_t* bgp = cw + (size_t)(gn + wn + col) * 1024 + quad * 8;

    f32x4 f4[8];
    bf16x8 bgA[4], bgB[4];
    f32x4 C[4][4] = {};

#define LOADX(tt) do {                                                      \
        _Pragma("unroll")                                                   \
        for (int kk = 0; kk < 8; ++kk)                                      \
            f4[kk] = *(const f32x4*)(xsrc + (size_t)((tt) * 64 + kk) * 1024); \
    } while (0)

#define WRITEA(dst) do {                                                    \
        _Pragma("unroll")                                                   \
        for (int mm = 0; mm < 4; ++mm) {                                    \
            bf16x8 w8;                                                      \
            _Pragma("unroll")                                               \
            for (int kk = 0; kk < 8; ++kk) w8[kk] = (bf16_t)f4[kk][mm];     \
            const int r  = m4 + mm;                                         \
            const int ss = (tid & 7) ^ (r & 7);                             \
            *(bf16x8*)((dst) + r * 64 + ss * 8) = w8;                       \
        }                                                                   \
    } while (0)

#define LOADBG(dst, tt, kss) do {                                           \
        _Pragma("unroll")                                                   \
        for (int ni = 0; ni < 4; ++ni)                                      \
            dst[ni] = *(const bf16x8*)(bgp + (size_t)(ni * 16) * 1024       \
                                       + (tt) * 64 + (kss) * 32);           \
    } while (0)

#define MFMA_HALF(kss, Ar, bg) do {                                         \
        bf16x8 af[4];                                                       \
        _Pragma("unroll")                                                   \
        for (int mi = 0; mi < 4; ++mi) {                                    \
            const int r  = wm + mi * 16 + col;                              \
            const int ph = ((kss) * 4 + quad) ^ (r & 7);                    \
            af[mi] = *(const bf16x8*)((Ar) + r * 64 + ph * 8);              \
        }                                                                   \
        _Pragma("unroll")                                                   \
        for (int mi = 0; mi < 4; ++mi)                                      \
            _Pragma("unroll")                                               \
            for (int ni = 0; ni < 4; ++ni)                                  \
                C[mi][ni] = __builtin_amdgcn_mfma_f32_16x16x32_bf16(        \
                    af[mi], bg[ni], C[mi][ni], 0, 0, 0);                    \
    } while (0)

    // ---- prologue ----
    LOADX(0);
    LOADBG(bgA, 0, 0);          // B(0, ks0)
    WRITEA(A0);                 // compiler waits on x(0) here
    LOADX(1);                   // in flight across tile 0
    asm volatile("s_waitcnt lgkmcnt(0)" ::: "memory");
    __builtin_amdgcn_s_barrier();

#pragma unroll 1
    for (int t = 0; t < 16; ++t) {
        bf16_t* Ar = (t & 1) ? A1 : A0;     // holds A(t)
        bf16_t* Aw = (t & 1) ? A0 : A1;     // fully consumed last tile
        if (t + 1 < 16) WRITEA(Aw);         // A(t+1) from f4 (compiler-counted wait)
        if (t + 2 < 16) LOADX(t + 2);
        LOADBG(bgB, t, 1);                  // B(t, ks1), lands during ks0 MFMAs
        MFMA_HALF(0, Ar, bgA);
        if (t + 1 < 16) LOADBG(bgA, t + 1, 0);  // B(t+1, ks0), lands during ks1 MFMAs
        MFMA_HALF(1, Ar, bgB);
        asm volatile("s_waitcnt lgkmcnt(0)" ::: "memory");  // A(t+1) writes visible
        __builtin_amdgcn_s_barrier();
    }
#undef LOADX
#undef WRITEA
#undef LOADBG
#undef MFMA_HALF

    // ---- epilogue: fold 128 cols -> per-pixel (s1,s2,s3) partials ----
    float cb[4], uv[4];
#pragma unroll
    for (int ni = 0; ni < 4; ++ni) {
        const int og = gn + wn + ni * 16 + col;
        cb[ni] = conv_b[og];
        uv[ni] = u[b * EMBED + og];
    }
    float* part = (float*)(smem + 32768);   // [2 n-halves][128 rows][3]
#pragma unroll
    for (int mi = 0; mi < 4; ++mi)
#pragma unroll
        for (int r = 0; r < 4; ++r) {
            float a = 0.f, sq = 0.f, d = 0.f;
#pragma unroll
            for (int ni = 0; ni < 4; ++ni) {
                float v = C[mi][ni][r] + cb[ni];
                a += v; sq += v * v; d += v * uv[ni];
            }
#pragma unroll
            for (int off = 1; off < 16; off <<= 1) {
                a  += __shfl_xor(a, off, 64);
                sq += __shfl_xor(sq, off, 64);
                d  += __shfl_xor(d, off, 64);
            }
            if (col == 0) {
                const int row = wm + mi * 16 + quad * 4 + r;
                float* pp = part + ((wv & 1) * 128 + row) * 3;
                pp[0] = a; pp[1] = sq; pp[2] = d;
            }
        }
    __syncthreads();
    if (tid < 128) {
        const float* p0 = part + tid * 3;
        const float* p1 = part + (128 + tid) * 3;
        const size_t pix = (size_t)gm + tid;
        partial[(size_t)(0 * 6 + nt) * 32768 + pix] = p0[0] + p1[0];
        partial[(size_t)(1 * 6 + nt) * 32768 + pix] = p0[1] + p1[1];
        partial[(size_t)(2 * 6 + nt) * 32768 + pix] = p0[2] + p1[2];
    }
}

// ---------------- K3: combine partials -> scores -> softmax ----------------
__global__ __launch_bounds__(1024)
void k_final(const float* __restrict__ partial, const float* __restrict__ u,
             float* __restrict__ out) {
    __shared__ float red[16];
    __shared__ float bc[3];
    const int b = blockIdx.x, t = threadIdx.x;
    const int lane = t & 63, wid = t >> 6;

    float pu = (t < EMBED) ? u[b * EMBED + t] : 0.f;
#pragma unroll
    for (int off = 1; off < 64; off <<= 1) pu += __shfl_xor(pu, off, 64);
    if (lane == 0) red[wid] = pu;
    __syncthreads();
    if (t == 0) { float s = 0.f; for (int i = 0; i < 16; ++i) s += red[i]; bc[0] = s; }
    __syncthreads();
    const float Su = bc[0];

    const size_t m = (size_t)b * 1024 + t;
    float S1 = 0.f, S2 = 0.f, S3 = 0.f;
#pragma unroll
    for (int nt = 0; nt < 6; ++nt) {
        S1 += partial[(size_t)(0 * 6 + nt) * 32768 + m];
        S2 += partial[(size_t)(1 * 6 + nt) * 32768 + m];
        S3 += partial[(size_t)(2 * 6 + nt) * 32768 + m];
    }
    const float mu  = S1 * (1.f / 768.f);
    const float var = S2 * (1.f / 768.f) - mu * mu;
    const float sc  = 0.035355339059327376f * (S3 - mu * Su) * rsqrtf(var + 1e-5f);

    float mx = sc;
#pragma unroll
    for (int off = 1; off < 64; off <<= 1) mx = fmaxf(mx, __shfl_xor(mx, off, 64));
    if (lane == 0) red[wid] = mx;
    __syncthreads();
    if (t == 0) { float mm = -1e30f; for (int i = 0; i < 16; ++i) mm = fmaxf(mm, red[i]); bc[1] = mm; }
    __syncthreads();
    const float e = __expf(sc - bc[1]);
    float ss = e;
#pragma unroll
    for (int off = 1; off < 64; off <<= 1) ss += __shfl_xor(ss, off, 64);
    __syncthreads();
    if (lane == 0) red[wid] = ss;
    __syncthreads();
    if (t == 0) { float s = 0.f; for (int i = 0; i < 16; ++i) s += red[i]; bc[2] = s; }
    __syncthreads();
    out[m] = e / bc[2];
}

extern "C" void kernel_launch(void* const* d_in, const int* in_sizes, int n_in,
                              void* d_out, int out_size, void* d_ws, size_t ws_size,
                              hipStream_t stream) {
    const float* x      = (const float*)d_in[0];
    const float* gender = (const float*)d_in[1];
    const float* conv_w = (const float*)d_in[2];
    const float* conv_b = (const float*)d_in[3];
    const float* ln_g   = (const float*)d_in[4];
    // d_in[5] = ln_b : drops out of softmax
    const float* cls    = (const float*)d_in[6];
    const float* qkv_w  = (const float*)d_in[7];
    const float* qkv_b  = (const float*)d_in[8];
    float* out = (float*)d_out;

    char* ws = (char*)d_ws;
    bf16_t* cw      = (bf16_t*)ws;                 //  1,572,864 B
    float*  q0b     = (float*)(ws + 1572864);      //    102,400 B
    float*  u       = (float*)(ws + 1675264);      //     98,304 B
    float*  partial = (float*)(ws + 1773568);      //  2,359,296 B (3 qty x 6 nt x 32768)

    hipLaunchKernelGGL(k_prep,  dim3(3272),  dim3(256),  0, stream,
                       conv_w, cw, qkv_w, qkv_b, cls, gender, q0b);
    hipLaunchKernelGGL(k_u,     dim3(768),   dim3(256),  0, stream, qkv_w, q0b, ln_g, u);
    hipLaunchKernelGGL(k_main,  dim3(1536),  dim3(256),  0, stream, x, cw, conv_b, u, partial);
    hipLaunchKernelGGL(k_final, dim3(32),    dim3(1024), 0, stream, partial, u, out);
}

// Round 7
// 296.595 us; speedup vs baseline: 1.2500x; 1.2500x over previous
//
#include <hip/hip_runtime.h>
#include <hip/hip_bf16.h>

#define EMBED 768
#define DIMQ  800
#define INC   1024
#define NPIX  1024

typedef __bf16 bf16_t;
typedef __bf16 bf16x8 __attribute__((ext_vector_type(8)));
typedef __bf16 bf16x2 __attribute__((ext_vector_type(2)));
typedef float  f32x4  __attribute__((ext_vector_type(4)));

#define GLD_LDS(gp, lp) __builtin_amdgcn_global_load_lds( \
    (const __attribute__((address_space(1))) void*)(gp),  \
    (__attribute__((address_space(3))) void*)(lp), 16, 0, 0)

// ---------------- K0: x transpose->bf16 (oct-permuted) + cw convert (oct-permuted) + q0 ----------------
// xT[b][m][k] with k-octet slot = oct ^ (m&7) within each 64k group; cw same with (n&7).
// Write phase emits one contiguous 128B span per row per 8 lanes (full-line HBM writes).
__global__ __launch_bounds__(256)
void k_prep(const float* __restrict__ x, bf16_t* __restrict__ xT,
            const float* __restrict__ w, bf16_t* __restrict__ cw,
            const float* __restrict__ qkv_w, const float* __restrict__ qkv_b,
            const float* __restrict__ cls, const float* __restrict__ gender,
            float* __restrict__ q0b) {
    __shared__ __align__(16) unsigned int tile[64 * 36];   // 64 m-rows x (32 dw + 4 pad)
    const int bi = blockIdx.x;
    const int t  = threadIdx.x;
    if (bi < 8192) {
        // ---- transpose one (b, 64k, 64m) tile ----
        const int b  = bi >> 8;
        const int k0 = ((bi >> 4) & 15) * 64;
        const int m0 = (bi & 15) * 64;
        const int m_l = t & 63;
        const int wv  = t >> 6;
        const float* src = x + ((size_t)(b * 1024 + k0 + wv * 16) * 1024) + m0 + m_l;
        bf16x2* trow = (bf16x2*)tile;
#pragma unroll
        for (int i = 0; i < 8; ++i) {
            float a0 = src[(size_t)(2 * i) * 1024];
            float a1 = src[(size_t)(2 * i + 1) * 1024];
            bf16x2 p; p[0] = (bf16_t)a0; p[1] = (bf16_t)a1;
            trow[m_l * 36 + wv * 8 + i] = p;     // dw: m*36 + wv*8 + i  (stride 36 dw!)
        }
        __syncthreads();
        // write: 8 consecutive lanes cover one row's full 64-k group (128B line),
        // oct-XOR permute stays inside the span.
        const int j = t & 7;                     // k-oct
#pragma unroll
        for (int rep = 0; rep < 2; ++rep) {
            const int m_r = (t >> 3) + rep * 32;
            bf16x8 v = *(const bf16x8*)&tile[m_r * 36 + j * 4];
            const int slot = j ^ (m_r & 7);
            bf16_t* drow = xT + ((size_t)(b * 1024 + m0 + m_r) * 1024) + k0;
            *(bf16x8*)(drow + slot * 8) = v;
        }
    } else if (bi < 8392) {
        // ---- q0b[b*800+i] = (Wq t0[b] + bq)[i] ----
        const int wv = t >> 6, tl = t & 63;
        const int i = (bi - 8192) * 4 + wv;           // 0..799
        const float* row = qkv_w + (size_t)i * DIMQ;
        float ps = 0.f;
        for (int j2 = tl; j2 < EMBED; j2 += 64) ps += row[j2] * cls[j2];
#pragma unroll
        for (int off = 1; off < 64; off <<= 1) ps += __shfl_xor(ps, off, 64);
        if (tl < 32) {
            float g = 0.f;
#pragma unroll
            for (int j2 = 0; j2 < 32; ++j2) g += row[EMBED + j2] * gender[tl * 32 + j2];
            q0b[tl * DIMQ + i] = ps + g + qkv_b[i];
        }
    } else {
        // ---- cw convert, oct slot = j ^ (n&7) ----
        const int i = (bi - 8392) * 256 + t;          // dst flat index
        const int n = i >> 10, k = i & 1023;
        const int s = (k >> 3) & 7;
        const int src_k = (k & ~63) | (((s ^ (n & 7)) & 7) << 3) | (k & 7);
        cw[i] = (bf16_t)w[(size_t)n * 1024 + src_k];
    }
}

// ---------------- K1: u[b][j] = ln_g[j] * sum_o Wk[o][j] q0[b][o] ----------------
__global__ __launch_bounds__(256)
void k_u(const float* __restrict__ qkv_w, const float* __restrict__ q0b,
         const float* __restrict__ ln_g, float* __restrict__ u) {
    __shared__ float q0s[DIMQ];
    __shared__ float sh[8][33];
    int t = threadIdx.x;
    int b  = blockIdx.x / 24;
    int j0 = (blockIdx.x % 24) * 32;
    for (int i = t; i < DIMQ; i += 256) q0s[i] = q0b[b * DIMQ + i];
    __syncthreads();
    int j_l = t & 31, os = t >> 5;
    const float* wk = qkv_w + (size_t)DIMQ * DIMQ;
    const float* wp = wk + (size_t)(os * 100) * DIMQ + j0 + j_l;
    float acc = 0.f;
#pragma unroll 4
    for (int i = 0; i < 100; ++i) acc += wp[(size_t)i * DIMQ] * q0s[os * 100 + i];
    sh[os][j_l] = acc;
    __syncthreads();
    if (t < 32) {
        float s = 0.f;
#pragma unroll
        for (int o = 0; o < 8; ++o) s += sh[o][t];
        u[b * EMBED + j0 + t] = s * ln_g[j0 + t];
    }
}

// ---------------- K2: 128x128xK1024 GEMM tile + column reduction (R0-proven) ----------------
__global__ __launch_bounds__(256, 3)
void k_main(const bf16_t* __restrict__ xT, const bf16_t* __restrict__ cw,
            const float* __restrict__ conv_b, const float* __restrict__ u,
            float* __restrict__ partial) {
    __shared__ __align__(1024) unsigned char smem[32768 + 3072];
    // A: 128 rows x 128 B @0 ; B: same @16384 ; part: 2x128x3 f32 @32768

    const int tid = threadIdx.x;
    // XCD swizzle: x8 = bi&7 -> XCD; sibling nt's consecutive on same XCD
    const int bi = blockIdx.x;
    const int x8 = bi & 7;
    const int s  = bi >> 3;
    const int nt = s % 6;
    const int mt = (s / 6) * 8 + x8;        // 0..255
    const int b  = mt >> 3;
    const int gm = mt * 128;                // global pixel row
    const int gn = nt * 128;                // global out-channel

    const int wv = tid >> 6;
    const int l  = tid & 63;
    const int lr = l >> 3;                  // row-in-8 for staging
    const int lc = l & 7;                   // oct slot for staging

    const int lane = l;
    const int col  = lane & 15;
    const int quad = lane >> 4;
    const int wm   = (wv >> 1) * 64;
    const int wn   = (wv & 1) * 64;

    bf16_t* A = (bf16_t*)smem;
    bf16_t* B = (bf16_t*)(smem + 16384);

    f32x4 C[4][4] = {};

    for (int kt = 0; kt < 16; ++kt) {
        const int ko = kt * 64;
        // ---- stage A+B via async DMA, linear lane mapping (swizzle pre-baked) ----
#pragma unroll
        for (int p = 0; p < 4; ++p) {
            const int r = p * 32 + wv * 8 + lr;
            GLD_LDS(xT + (size_t)(gm + r) * 1024 + ko + lc * 8, A + (p * 32 + wv * 8) * 64);
            GLD_LDS(cw + (size_t)(gn + r) * 1024 + ko + lc * 8, B + (p * 32 + wv * 8) * 64);
        }
        __syncthreads();
        // ---- 2 ks x 16 MFMA ----
#pragma unroll
        for (int ks = 0; ks < 2; ++ks) {
            bf16x8 af[4], bg[4];
#pragma unroll
            for (int mi = 0; mi < 4; ++mi) {
                const int r  = wm + mi * 16 + col;
                const int ph = (ks * 4 + quad) ^ (r & 7);
                af[mi] = *(const bf16x8*)(A + r * 64 + ph * 8);
            }
#pragma unroll
            for (int ni = 0; ni < 4; ++ni) {
                const int r  = wn + ni * 16 + col;
                const int ph = (ks * 4 + quad) ^ (r & 7);
                bg[ni] = *(const bf16x8*)(B + r * 64 + ph * 8);
            }
#pragma unroll
            for (int mi = 0; mi < 4; ++mi)
#pragma unroll
                for (int ni = 0; ni < 4; ++ni)
                    C[mi][ni] = __builtin_amdgcn_mfma_f32_16x16x32_bf16(af[mi], bg[ni], C[mi][ni], 0, 0, 0);
        }
        __syncthreads();
    }

    // ---- epilogue: fold 128 cols -> per-pixel (s1,s2,s3) partials ----
    float cb[4], uv[4];
#pragma unroll
    for (int ni = 0; ni < 4; ++ni) {
        const int og = gn + wn + ni * 16 + col;
        cb[ni] = conv_b[og];
        uv[ni] = u[b * EMBED + og];
    }
    float* part = (float*)(smem + 32768);   // [2 n-halves][128 rows][3]
#pragma unroll
    for (int mi = 0; mi < 4; ++mi)
#pragma unroll
        for (int r = 0; r < 4; ++r) {
            float a = 0.f, sq = 0.f, d = 0.f;
#pragma unroll
            for (int ni = 0; ni < 4; ++ni) {
                float v = C[mi][ni][r] + cb[ni];
                a += v; sq += v * v; d += v * uv[ni];
            }
#pragma unroll
            for (int off = 1; off < 16; off <<= 1) {
                a  += __shfl_xor(a, off, 64);
                sq += __shfl_xor(sq, off, 64);
                d  += __shfl_xor(d, off, 64);
            }
            if (col == 0) {
                const int row = wm + mi * 16 + quad * 4 + r;
                float* pp = part + ((wv & 1) * 128 + row) * 3;
                pp[0] = a; pp[1] = sq; pp[2] = d;
            }
        }
    __syncthreads();
    if (tid < 128) {
        const float* p0 = part + tid * 3;
        const float* p1 = part + (128 + tid) * 3;
        const size_t pix = (size_t)gm + tid;
        partial[(size_t)(0 * 6 + nt) * 32768 + pix] = p0[0] + p1[0];
        partial[(size_t)(1 * 6 + nt) * 32768 + pix] = p0[1] + p1[1];
        partial[(size_t)(2 * 6 + nt) * 32768 + pix] = p0[2] + p1[2];
    }
}

// ---------------- K3: combine partials -> scores -> softmax ----------------
__global__ __launch_bounds__(1024)
void k_final(const float* __restrict__ partial, const float* __restrict__ u,
             float* __restrict__ out) {
    __shared__ float red[16];
    __shared__ float bc[3];
    const int b = blockIdx.x, t = threadIdx.x;
    const int lane = t & 63, wid = t >> 6;

    float pu = (t < EMBED) ? u[b * EMBED + t] : 0.f;
#pragma unroll
    for (int off = 1; off < 64; off <<= 1) pu += __shfl_xor(pu, off, 64);
    if (lane == 0) red[wid] = pu;
    __syncthreads();
    if (t == 0) { float s = 0.f; for (int i = 0; i < 16; ++i) s += red[i]; bc[0] = s; }
    __syncthreads();
    const float Su = bc[0];

    const size_t m = (size_t)b * 1024 + t;
    float S1 = 0.f, S2 = 0.f, S3 = 0.f;
#pragma unroll
    for (int nt = 0; nt < 6; ++nt) {
        S1 += partial[(size_t)(0 * 6 + nt) * 32768 + m];
        S2 += partial[(size_t)(1 * 6 + nt) * 32768 + m];
        S3 += partial[(size_t)(2 * 6 + nt) * 32768 + m];
    }
    const float mu  = S1 * (1.f / 768.f);
    const float var = S2 * (1.f / 768.f) - mu * mu;
    const float sc  = 0.035355339059327376f * (S3 - mu * Su) * rsqrtf(var + 1e-5f);

    float mx = sc;
#pragma unroll
    for (int off = 1; off < 64; off <<= 1) mx = fmaxf(mx, __shfl_xor(mx, off, 64));
    if (lane == 0) red[wid] = mx;
    __syncthreads();
    if (t == 0) { float mm = -1e30f; for (int i = 0; i < 16; ++i) mm = fmaxf(mm, red[i]); bc[1] = mm; }
    __syncthreads();
    const float e = __expf(sc - bc[1]);
    float ss = e;
#pragma unroll
    for (int off = 1; off < 64; off <<= 1) ss += __shfl_xor(ss, off, 64);
    __syncthreads();
    if (lane == 0) red[wid] = ss;
    __syncthreads();
    if (t == 0) { float s = 0.f; for (int i = 0; i < 16; ++i) s += red[i]; bc[2] = s; }
    __syncthreads();
    out[m] = e / bc[2];
}

extern "C" void kernel_launch(void* const* d_in, const int* in_sizes, int n_in,
                              void* d_out, int out_size, void* d_ws, size_t ws_size,
                              hipStream_t stream) {
    const float* x      = (const float*)d_in[0];
    const float* gender = (const float*)d_in[1];
    const float* conv_w = (const float*)d_in[2];
    const float* conv_b = (const float*)d_in[3];
    const float* ln_g   = (const float*)d_in[4];
    // d_in[5] = ln_b : drops out of softmax
    const float* cls    = (const float*)d_in[6];
    const float* qkv_w  = (const float*)d_in[7];
    const float* qkv_b  = (const float*)d_in[8];
    float* out = (float*)d_out;

    char* ws = (char*)d_ws;
    bf16_t* cw      = (bf16_t*)ws;                 //  1,572,864 B
    float*  q0b     = (float*)(ws + 1572864);      //    102,400 B
    float*  u       = (float*)(ws + 1675264);      //     98,304 B
    float*  partial = (float*)(ws + 1773568);      //  2,359,296 B
    bf16_t* xT      = (bf16_t*)(ws + 4132864);     // 67,108,864 B (end ~71.2 MB)

    hipLaunchKernelGGL(k_prep,  dim3(11464), dim3(256),  0, stream,
                       x, xT, conv_w, cw, qkv_w, qkv_b, cls, gender, q0b);
    hipLaunchKernelGGL(k_u,     dim3(768),   dim3(256),  0, stream, qkv_w, q0b, ln_g, u);
    hipLaunchKernelGGL(k_main,  dim3(1536),  dim3(256),  0, stream, xT, cw, conv_b, u, partial);
    hipLaunchKernelGGL(k_final, dim3(32),    dim3(1024), 0, stream, partial, u, out);
}